// Round 4
// baseline (2948.973 us; speedup 1.0000x reference)
//
#include <hip/hip_runtime.h>

#define T_TOK 8192   // B*S tokens
#define DIM   768
#define NCB   8192   // codebook entries
#define KSEL  8
#define BT    64     // tokens per workgroup (1 per lane)
#define CTILE 32     // codes per block-tile (8 per wave)
#define BD    32     // d-chunk staged in LDS
#define BUFQ  768    // float4 per staging buffer: xs 512 + cs 256
#define MST   33     // merge row stride in floats

typedef float v2f __attribute__((ext_vector_type(2)));

// 16B global->LDS DMA. Dest is wave-uniform base + lane*16 (HW rule); all
// per-lane scatter lives in the GLOBAL source address.
__device__ __forceinline__ void gload16(const float* g, float4* l) {
  __builtin_amdgcn_global_load_lds(
      (const __attribute__((address_space(1))) void*)g,
      (__attribute__((address_space(3))) void*)l, 16, 0, 0);
}

// ---------------------------------------------------------------------------
// Kernel A: ||row||^2 — bit-exact modern-numpy pairwise_sum (npyv/AVX-512
// W=16) over t[k]=fl32(v*v). [frozen: R5 green — do not change rounding]
// ---------------------------------------------------------------------------
__global__ __launch_bounds__(256) void sq_pairwise_kernel(
    const float* __restrict__ cb, const float* __restrict__ x,
    float* __restrict__ c2out, float* __restrict__ x2out)
{
  #pragma clang fp contract(off)
  __shared__ float part[32][8];
  const int tid = threadIdx.x;
  const int row = blockIdx.x * 32 + (tid >> 3);       // 0..16383
  const int b   = tid & 7;                            // 96-block index
  const float* src = (row < NCB) ? (cb + (size_t)row * DIM)
                                 : (x + (size_t)(row - NCB) * DIM);
  const float* a = src + 96 * b;

  float s[16];
  #pragma unroll
  for (int l = 0; l < 16; ++l) {
    float v, t;
    v = a[l];       t = v * v; float r0 = t;
    v = a[64 + l];  t = v * v; r0 = r0 + t;
    v = a[80 + l];  t = v * v; r0 = r0 + t;
    v = a[16 + l];  t = v * v; float r1 = t;
    v = a[32 + l];  t = v * v; float r2 = t;
    v = a[48 + l];  t = v * v; float r3 = t;
    s[l] = (r0 + r1) + (r2 + r3);
  }
  float t1[8], t2[4];
  #pragma unroll
  for (int i = 0; i < 8; ++i) t1[i] = s[i] + s[i + 8];
  #pragma unroll
  for (int j = 0; j < 4; ++j) t2[j] = t1[j] + t1[j + 4];
  part[tid >> 3][b] = (t2[0] + t2[2]) + (t2[1] + t2[3]);
  __syncthreads();

  if (b == 0) {
    const float* p = part[tid >> 3];
    float res = ((p[0] + p[1]) + (p[2] + p[3])) + ((p[4] + p[5]) + (p[6] + p[7]));
    if (row < NCB) c2out[row] = res;
    else           x2out[row - NCB] = res;
  }
}

// ---------------------------------------------------------------------------
// Kernel B: split-K distance + per-split exact top-8.
// Frozen arithmetic (R5): unfused SSE1 4-lane comb (lane = k&3, ascending k),
// reduce (l0+l2)+(l1+l3), neg = fl(fl(2*xc-x2)-c2), key = -neg (exact).
// R4 structure: WAVE-UNIFORM CODE TILING. wave = 64 tokens (1/lane) x 8
// codes; block = 4 waves = 64 tok x 32 codes/tile. Each thread owns all 4
// SSE lanes of its (tok,code) pairs (accL lanes 0,1 / accH lanes 2,3,
// ascending d-quads) => bit-exact, no pair exchange. Code LDS reads are
// wave-uniform (HW broadcast, conflict-free, amortized over 64 lanes):
// ~0.56 B/MAC through LDS => VALU-bound. Distances finish in registers;
// per-thread top-8 scans its own 8 codes/tile from regs (ids ascend:
// n0 + w*8 + j over ascending tiles; strict < keeps lowest id on ties).
// Final: 4 candidate sets per token merged (val,id)-lex via LDS.
// ---------------------------------------------------------------------------
__global__ __launch_bounds__(256, 4) void dist_topk_kernel(
    const float* __restrict__ x, const float* __restrict__ cb,
    const float* __restrict__ c2g, const float* __restrict__ x2g,
    float* __restrict__ ws, int ncodes)
{
  #pragma clang fp contract(off)
  __shared__ float4 smem4[2 * BUFQ];             // 24576 B
  float* smem = (float*)smem4;
  // buf b: xs = smem4 + b*BUFQ ([q][t], 512 f4, 1024B per quad-row);
  //        cs = xs + 512 ([c][q], 256 f4, code c quad q at slot c*8+q)
  // post-loop overlay: md [64][MST] floats @0, mi [64][MST] ints @64*MST

  const int tid  = threadIdx.x;
  const int t0   = blockIdx.x * BT;
  const int nbeg = blockIdx.y * ncodes;
  const int lane = tid & 63;     // token within block
  const int w    = tid >> 6;     // wave id = code-group (8 codes)

  // DMA sources (lane-linear within wave; dest = uniform base + lane*16)
  const float* xrow = x + (size_t)(t0 + lane) * DIM;        // this lane's token
  const float* crow = cb + (size_t)(tid >> 3) * DIM + (tid & 7) * 4;
  float4* xdst = smem4 + (tid & ~63);            // + b*BUFQ (+256 for call 1)
  float4* cdst = smem4 + 512 + (tid & ~63);      // + b*BUFQ

  const float x2r = x2g[t0 + lane];

  float bdist[KSEL]; int bid[KSEL];
  #pragma unroll
  for (int i = 0; i < KSEL; ++i) { bdist[i] = __builtin_inff(); bid[i] = 0x7fffffff; }
  float bmax = __builtin_inff(); int bmaxid = 0x7fffffff; int bslot = 0;

  for (int n0 = nbeg; n0 < nbeg + ncodes; n0 += CTILE) {
    v2f accL[8], accH[8];          // SSE lanes (0,1) and (2,3) for 8 codes
    #pragma unroll
    for (int j = 0; j < 8; ++j) { accL[j] = (v2f)0.f; accH[j] = (v2f)0.f; }

    const size_t cb_tile = (size_t)n0 * DIM;
    {                              // stage chunk 0 -> buf0 (prev tile drained)
      gload16(xrow + w * 4,      xdst);
      gload16(xrow + 16 + w * 4, xdst + 256);
      gload16(crow + cb_tile,    cdst);
    }
    __syncthreads();               // chunk 0 visible (implicit vmcnt(0))

    for (int d0 = 0; d0 < DIM; d0 += BD) {
      const int buf = (d0 >> 5) & 1;
      const int dn = d0 + BD;
      if (dn < DIM) {              // issue next-chunk DMA into other buffer
        float4* xd = xdst + (buf ^ 1) * BUFQ;
        gload16(xrow + dn + w * 4,      xd);
        gload16(xrow + dn + 16 + w * 4, xd + 256);
        gload16(crow + cb_tile + dn,    cdst + (buf ^ 1) * BUFQ);
      }

      // x: lane's token quad q at byte q*1024 + lane*16 (2-way, free)
      // c: code (w*8+j) quad q at byte (w*8+j)*128 + q*16 (uniform bcast)
      const char* xb  = (const char*)(smem4 + buf * BUFQ) + lane * 16;
      const char* cbp = (const char*)(smem4 + buf * BUFQ + 512) + w * 1024;
      #pragma unroll
      for (int q = 0; q < 8; ++q) {
        const float4 xv = *(const float4*)(xb + q * 1024);
        v2f xlo, xhi;
        xlo[0] = xv.x; xlo[1] = xv.y;
        xhi[0] = xv.z; xhi[1] = xv.w;
        #pragma unroll
        for (int j = 0; j < 8; ++j) {
          const float4 cv = *(const float4*)(cbp + j * 128 + q * 16);
          v2f clo, chi, p;
          clo[0] = cv.x; clo[1] = cv.y;
          chi[0] = cv.z; chi[1] = cv.w;
          p = xlo * clo; accL[j] = accL[j] + p;   // independent fl32 mul/add
          p = xhi * chi; accH[j] = accH[j] + p;
        }
      }
      __syncthreads();             // my reads done + next-chunk DMA landed
    }

    // ---- combine (frozen order) + register-resident top-8 scan ----
    #pragma unroll
    for (int j = 0; j < 8; ++j) {
      const float c2 = c2g[n0 + w * 8 + j];
      // einsum reduce (l0+l2)+(l1+l3), then literal numpy combine
      const float xc = (accL[j][0] + accH[j][0]) + (accL[j][1] + accH[j][1]);
      const float s  = 2.0f * xc - x2r;
      const float dval = -(s - c2);
      const int   id   = n0 + w * 8 + j;
      if (dval < bmax) {
        #pragma unroll
        for (int q = 0; q < KSEL; ++q)
          if (q == bslot) { bdist[q] = dval; bid[q] = id; }
        bmax = bdist[0]; bmaxid = bid[0]; bslot = 0;
        #pragma unroll
        for (int q = 1; q < KSEL; ++q)
          if (bdist[q] > bmax || (bdist[q] == bmax && bid[q] > bmaxid)) {
            bmax = bdist[q]; bmaxid = bid[q]; bslot = q;
          }
      }
    }
    // next tile's staging is safe: last chunk's barrier drained all reads
  }

  // ---- merge 4 waves x 8 -> this split's top-8 per token; write to ws ----
  float* md = smem;                    // [64][MST]
  int*   mi = (int*)smem + 64 * MST;   // [64][MST]
  #pragma unroll
  for (int j = 0; j < KSEL; ++j) {
    md[lane * MST + w * KSEL + j] = bdist[j];
    mi[lane * MST + w * KSEL + j] = bid[j];
  }
  __syncthreads();
  if (tid < BT) {
    float* mdt = md + tid * MST;
    int*   mit = mi + tid * MST;
    const size_t base = ((size_t)blockIdx.y * T_TOK + (t0 + tid)) * 16;
    for (int r = 0; r < KSEL; ++r) {
      float best = __builtin_inff(); int bestid = 0x7fffffff; int bs = 0;
      for (int s = 0; s < 32; ++s) {
        const float dv = mdt[s]; const int iv = mit[s];
        if (dv < best || (dv == best && iv < bestid)) { best = dv; bestid = iv; bs = s; }
      }
      mdt[bs] = __builtin_inff();
      ws[base + r] = best;
      ((int*)ws)[base + 8 + r] = bestid;
    }
  }
}

// ---------------------------------------------------------------------------
// Kernel C: exact (val,id)-lex merge of nsplit*8 candidates -> final ids,
// fused with the gather-mean of the 8 selected rows.
// ---------------------------------------------------------------------------
__global__ __launch_bounds__(192) void merge_gather_kernel(
    const float* __restrict__ cb, const float* __restrict__ ws,
    float* __restrict__ out, float* __restrict__ out_ids, int nsplit)
{
  __shared__ float mv[64];
  __shared__ int   mid[64];
  __shared__ int   ssel[KSEL];

  const int t   = blockIdx.x;
  const int tid = threadIdx.x;
  const int ncand = nsplit * KSEL;

  if (tid < ncand) {
    const int s = tid >> 3, r = tid & 7;
    const size_t base = ((size_t)s * T_TOK + t) * 16;
    mv[tid]  = ws[base + r];
    mid[tid] = ((const int*)ws)[base + 8 + r];
  }
  __syncthreads();

  if (tid == 0) {
    for (int r = 0; r < KSEL; ++r) {
      float best = __builtin_inff(); int bestid = 0x7fffffff; int bs = 0;
      for (int s = 0; s < ncand; ++s) {
        const float dv = mv[s]; const int iv = mid[s];
        if (dv < best || (dv == best && iv < bestid)) { best = dv; bestid = iv; bs = s; }
      }
      mv[bs] = __builtin_inff();
      ssel[r] = bestid;
      out_ids[(size_t)t * KSEL + r] = (float)bestid;
    }
  }
  __syncthreads();

  float4 s4 = make_float4(0.f, 0.f, 0.f, 0.f);
  #pragma unroll
  for (int r = 0; r < KSEL; ++r) {
    const float4 v = *(const float4*)(cb + (size_t)ssel[r] * DIM + tid * 4);
    s4.x += v.x; s4.y += v.y; s4.z += v.z; s4.w += v.w;
  }
  s4.x *= 0.125f; s4.y *= 0.125f; s4.z *= 0.125f; s4.w *= 0.125f;
  *(float4*)(out + (size_t)t * DIM + tid * 4) = s4;
}

extern "C" void kernel_launch(void* const* d_in, const int* in_sizes, int n_in,
                              void* d_out, int out_size, void* d_ws, size_t ws_size,
                              hipStream_t stream) {
  (void)in_sizes; (void)n_in; (void)out_size;
  const float* x   = (const float*)d_in[0];
  const float* cbk = (const float*)d_in[1];
  float* out     = (float*)d_out;
  float* c2buf   = out;                   // out[0:8192], overwritten later
  float* x2buf   = out + NCB;             // out[8192:16384], overwritten later
  float* out_ids = out + (size_t)T_TOK * DIM;
  float* ws      = (float*)d_ws;

  int nsplit = 1;
  for (int s = 8; s >= 1; s >>= 1) {
    if ((size_t)s * T_TOK * 16 * 4 <= ws_size) { nsplit = s; break; }
  }
  const int ncodes = NCB / nsplit;        // multiple of CTILE for all nsplit

  sq_pairwise_kernel<<<(NCB + T_TOK) / 32, 256, 0, stream>>>(cbk, x, c2buf, x2buf);
  dist_topk_kernel<<<dim3(T_TOK / BT, nsplit), 256, 0, stream>>>(
      x, cbk, c2buf, x2buf, ws, ncodes);
  merge_gather_kernel<<<T_TOK, 192, 0, stream>>>(cbk, ws, out, out_ids, nsplit);
}